// Round 1
// baseline (777.358 us; speedup 1.0000x reference)
//
#include <hip/hip_runtime.h>
#include <math.h>

#define NPTS 768
#define CCH  128
#define NP   56    // psi padded to 56 (55 monomials + 1 zero pad), 14 float4
#define TILE 128

// ---------------------------------------------------------------------------
// P1: norms; C1 (C x 10); A2/B2 = W2@C1 (+bias fold); C2 (C x 55, padded 56)
// Single block, 256 threads.
// ---------------------------------------------------------------------------
__global__ void k_pre1(const float* __restrict__ x,
                       const float* __restrict__ Wa1, const float* __restrict__ ba1,
                       const float* __restrict__ Wb1, const float* __restrict__ bb1,
                       const float* __restrict__ Wa2, const float* __restrict__ ba2,
                       const float* __restrict__ Wb2, const float* __restrict__ bb2,
                       float* __restrict__ norms, float* __restrict__ C2g) {
  __shared__ float C1[CCH][10];
  __shared__ float A2[CCH][10];
  __shared__ float B2[CCH][10];
  const int tid = threadIdx.x;

  for (int i = tid; i < NPTS; i += 256) {
    float a = x[3*i], b = x[3*i+1], c = x[3*i+2];
    norms[i] = sqrtf(a*a + b*b + c*c);
  }
  if (tid < CCH) {
    const int c = tid;
    float Aa[4] = {Wa1[3*c], Wa1[3*c+1], Wa1[3*c+2], ba1[c]};
    float Bb[4] = {Wb1[3*c], Wb1[3*c+1], Wb1[3*c+2], bb1[c]};
    int t = 0;
    for (int p = 0; p < 4; ++p)
      for (int q = p; q < 4; ++q) {
        C1[c][t] = (p == q) ? Aa[p]*Bb[p] : Aa[p]*Bb[q] + Aa[q]*Bb[p];
        ++t;
      }
  }
  __syncthreads();
  for (int idx = tid; idx < CCH*10; idx += 256) {
    const int c = idx / 10, t = idx % 10;
    float sa = 0.f, sb = 0.f;
    for (int k = 0; k < CCH; ++k) {
      const float v = C1[k][t];
      sa += Wa2[c*CCH + k] * v;
      sb += Wb2[c*CCH + k] * v;
    }
    if (t == 9) { sa += ba2[c]; sb += bb2[c]; }   // phi_9 == 1 (constant)
    A2[c][t] = sa; B2[c][t] = sb;
  }
  __syncthreads();
  for (int idx = tid; idx < CCH*NP; idx += 256) {
    const int c = idx / NP, j = idx % NP;
    float val = 0.f;
    if (j < 55) {
      int jj = j, r = 0;
      while (jj >= 10 - r) { jj -= (10 - r); ++r; }
      const int s = r + jj;
      val = (r == s) ? A2[c][r]*B2[c][r]
                     : A2[c][r]*B2[c][s] + A2[c][s]*B2[c][r];
    }
    C2g[c*NP + j] = val;
  }
}

// ---------------------------------------------------------------------------
// P2: A3 = Wa3@C2 (+ba3 fold at psi_54 == 1), B3 likewise. 128 blocks x 64 thr.
// ---------------------------------------------------------------------------
__global__ void k_pre2(const float* __restrict__ Wa3, const float* __restrict__ ba3,
                       const float* __restrict__ Wb3, const float* __restrict__ bb3,
                       const float* __restrict__ C2g,
                       float* __restrict__ A3g, float* __restrict__ B3g) {
  const int c = blockIdx.x;
  const int j = threadIdx.x;
  if (j >= NP) return;
  float sa = 0.f, sb = 0.f;
  if (j < 55) {
    for (int k = 0; k < CCH; ++k) {
      const float v = C2g[k*NP + j];
      sa += Wa3[c*CCH + k] * v;
      sb += Wb3[c*CCH + k] * v;
    }
    if (j == 54) { sa += ba3[c]; sb += bb3[c]; }  // psi_54 = phi_9*phi_9 = 1
  }
  A3g[c*NP + j] = sa;
  B3g[c*NP + j] = sb;
}

// ---------------------------------------------------------------------------
// Shared device helper: build one psi row into LDS for pair (row m, col n).
// u = ||x_m|| (row norm), v = ||x_n|| (col norm). Same expression in both
// sweep kernels -> bitwise identical h3 between passes.
// ---------------------------------------------------------------------------
__device__ __forceinline__ void build_psi(float* __restrict__ row,
                                          float u, float v, float dot) {
  float d2 = u*u + v*v - 2.f*dot;
  float d  = (d2 > 0.f) ? sqrtf(d2) : 0.f;
  float phi[10] = {d*d, d*u, d*v, d, u*u, u*v, u, v*v, v, 1.f};
  int jj = 0;
  #pragma unroll
  for (int r = 0; r < 10; ++r)
    #pragma unroll
    for (int s = r; s < 10; ++s)
      row[jj++] = phi[r]*phi[s];
  row[55] = 0.f;  // pad (A3/B3 pad coeff is 0, but keep LDS finite)
}

// ---------------------------------------------------------------------------
// Kernel A: block = row m, 128 threads = channels. Online softmax over n.
// Writes M[m,c], Sinv[m,c].
// ---------------------------------------------------------------------------
__global__ __launch_bounds__(128) void k_rows(
    const float* __restrict__ x, const float* __restrict__ norms,
    const float* __restrict__ A3g, const float* __restrict__ B3g,
    float* __restrict__ Mout, float* __restrict__ Sinv) {
  __shared__ __align__(16) float psi[TILE][NP];
  __shared__ float xs[NPTS*3];
  __shared__ float ns[NPTS];
  const int tid = threadIdx.x;
  const int m = blockIdx.x;

  for (int i = tid; i < 3*NPTS; i += 128) xs[i] = x[i];
  for (int i = tid; i < NPTS; i += 128) ns[i] = norms[i];

  float4 a3[NP/4], b3[NP/4];
  const float4* Av = reinterpret_cast<const float4*>(A3g + tid*NP);
  const float4* Bv = reinterpret_cast<const float4*>(B3g + tid*NP);
  #pragma unroll
  for (int j = 0; j < NP/4; ++j) { a3[j] = Av[j]; b3[j] = Bv[j]; }
  __syncthreads();

  const float xm0 = xs[3*m], xm1 = xs[3*m+1], xm2 = xs[3*m+2];
  const float u = ns[m];
  float mrun = -INFINITY, srun = 0.f;

  for (int t0 = 0; t0 < NPTS; t0 += TILE) {
    {
      const int n = t0 + tid;
      const float dot = xm0*xs[3*n] + xm1*xs[3*n+1] + xm2*xs[3*n+2];
      build_psi(psi[tid], u, ns[n], dot);
    }
    __syncthreads();
    for (int nn = 0; nn < TILE; ++nn) {
      const float4* pv = reinterpret_cast<const float4*>(psi[nn]);
      float la = 0.f, lb = 0.f;
      #pragma unroll
      for (int j = 0; j < NP/4; ++j) {
        const float4 p = pv[j];
        la += a3[j].x*p.x + a3[j].y*p.y + a3[j].z*p.z + a3[j].w*p.w;
        lb += b3[j].x*p.x + b3[j].y*p.y + b3[j].z*p.z + b3[j].w*p.w;
      }
      const float h = la*lb;
      const float mnew = fmaxf(mrun, h);
      srun = srun*__expf(mrun - mnew) + __expf(h - mnew);
      mrun = mnew;
    }
    __syncthreads();
  }
  Mout[m*CCH + tid] = mrun;
  Sinv[m*CCH + tid] = 1.f / srun;
}

// ---------------------------------------------------------------------------
// Kernel B: block = col n, 128 threads = channels. Recomputes h3 (bitwise
// identical), accumulates colsum[n,c] = sum_m exp(h3 - M[m,c]) * Sinv[m,c].
// ---------------------------------------------------------------------------
__global__ __launch_bounds__(128) void k_cols(
    const float* __restrict__ x, const float* __restrict__ norms,
    const float* __restrict__ A3g, const float* __restrict__ B3g,
    const float* __restrict__ Mbuf, const float* __restrict__ Sinv,
    float* __restrict__ colsum) {
  __shared__ __align__(16) float psi[TILE][NP];
  __shared__ float xs[NPTS*3];
  __shared__ float ns[NPTS];
  const int tid = threadIdx.x;
  const int n = blockIdx.x;

  for (int i = tid; i < 3*NPTS; i += 128) xs[i] = x[i];
  for (int i = tid; i < NPTS; i += 128) ns[i] = norms[i];

  float4 a3[NP/4], b3[NP/4];
  const float4* Av = reinterpret_cast<const float4*>(A3g + tid*NP);
  const float4* Bv = reinterpret_cast<const float4*>(B3g + tid*NP);
  #pragma unroll
  for (int j = 0; j < NP/4; ++j) { a3[j] = Av[j]; b3[j] = Bv[j]; }
  __syncthreads();

  const float xn0 = xs[3*n], xn1 = xs[3*n+1], xn2 = xs[3*n+2];
  const float v = ns[n];
  float csum = 0.f;

  for (int t0 = 0; t0 < NPTS; t0 += TILE) {
    {
      const int mm = t0 + tid;  // row index
      const float dot = xs[3*mm]*xn0 + xs[3*mm+1]*xn1 + xs[3*mm+2]*xn2;
      build_psi(psi[tid], ns[mm], v, dot);
    }
    __syncthreads();
    for (int mm2 = 0; mm2 < TILE; ++mm2) {
      const float4* pv = reinterpret_cast<const float4*>(psi[mm2]);
      float la = 0.f, lb = 0.f;
      #pragma unroll
      for (int j = 0; j < NP/4; ++j) {
        const float4 p = pv[j];
        la += a3[j].x*p.x + a3[j].y*p.y + a3[j].z*p.z + a3[j].w*p.w;
        lb += b3[j].x*p.x + b3[j].y*p.y + b3[j].z*p.z + b3[j].w*p.w;
      }
      const float h = la*lb;
      const int mg = t0 + mm2;
      csum += __expf(h - Mbuf[mg*CCH + tid]) * Sinv[mg*CCH + tid];
    }
    __syncthreads();
  }
  colsum[n*CCH + tid] = csum;
}

// ---------------------------------------------------------------------------
// Final: agg[i,c] = sum_n colsum[n,c]*x[n,i]; out[o,i] = sum_c Wf[o,c]*agg[i,c]
// out layout: [x0,x1,x2, o00,o01,o02, o10,o11,o12]. 1 block, 128 threads.
// ---------------------------------------------------------------------------
__global__ __launch_bounds__(128) void k_final(
    const float* __restrict__ x, const float* __restrict__ colsum,
    const float* __restrict__ Wf, float* __restrict__ out) {
  __shared__ float xs[NPTS*3];
  __shared__ float red[CCH][6];
  const int c = threadIdx.x;
  for (int i = c; i < 3*NPTS; i += 128) xs[i] = x[i];
  __syncthreads();
  float a0 = 0.f, a1 = 0.f, a2 = 0.f;
  for (int n = 0; n < NPTS; ++n) {
    const float cs = colsum[n*CCH + c];
    a0 += cs*xs[3*n]; a1 += cs*xs[3*n+1]; a2 += cs*xs[3*n+2];
  }
  const float w0 = Wf[c], w1 = Wf[CCH + c];
  red[c][0] = w0*a0; red[c][1] = w0*a1; red[c][2] = w0*a2;
  red[c][3] = w1*a0; red[c][4] = w1*a1; red[c][5] = w1*a2;
  __syncthreads();
  if (c < 6) {
    float s = 0.f;
    for (int k = 0; k < CCH; ++k) s += red[k][c];
    out[3 + c] = s;
  }
  if (c < 3) out[c] = xs[c];
}

// ---------------------------------------------------------------------------
extern "C" void kernel_launch(void* const* d_in, const int* in_sizes, int n_in,
                              void* d_out, int out_size, void* d_ws, size_t ws_size,
                              hipStream_t stream) {
  const float* x   = (const float*)d_in[0];
  const float* Wa1 = (const float*)d_in[1];
  const float* ba1 = (const float*)d_in[2];
  const float* Wb1 = (const float*)d_in[3];
  const float* bb1 = (const float*)d_in[4];
  const float* Wa2 = (const float*)d_in[5];
  const float* ba2 = (const float*)d_in[6];
  const float* Wb2 = (const float*)d_in[7];
  const float* bb2 = (const float*)d_in[8];
  const float* Wa3 = (const float*)d_in[9];
  const float* ba3 = (const float*)d_in[10];
  const float* Wb3 = (const float*)d_in[11];
  const float* bb3 = (const float*)d_in[12];
  const float* Wf  = (const float*)d_in[13];
  float* out = (float*)d_out;

  float* ws     = (float*)d_ws;
  float* norms  = ws;                 // 768
  float* A3g    = norms + NPTS;       // 128*56
  float* B3g    = A3g + CCH*NP;       // 128*56
  float* C2g    = B3g + CCH*NP;       // 128*56
  float* Mbuf   = C2g + CCH*NP;       // 768*128
  float* Sinvb  = Mbuf + NPTS*CCH;    // 768*128
  float* colsum = Sinvb + NPTS*CCH;   // 768*128   (total ~1.27 MB)

  hipLaunchKernelGGL(k_pre1, dim3(1), dim3(256), 0, stream,
                     x, Wa1, ba1, Wb1, bb1, Wa2, ba2, Wb2, bb2, norms, C2g);
  hipLaunchKernelGGL(k_pre2, dim3(CCH), dim3(64), 0, stream,
                     Wa3, ba3, Wb3, bb3, C2g, A3g, B3g);
  hipLaunchKernelGGL(k_rows, dim3(NPTS), dim3(128), 0, stream,
                     x, norms, A3g, B3g, Mbuf, Sinvb);
  hipLaunchKernelGGL(k_cols, dim3(NPTS), dim3(128), 0, stream,
                     x, norms, A3g, B3g, Mbuf, Sinvb, colsum);
  hipLaunchKernelGGL(k_final, dim3(1), dim3(128), 0, stream,
                     x, colsum, Wf, out);
}

// Round 2
// 302.319 us; speedup vs baseline: 2.5713x; 2.5713x over previous
//
#include <hip/hip_runtime.h>
#include <math.h>

#define NPTS 768
#define CCH  128
#define NM4  36    // 35 deg<=4 monomials in (d,u,v) + 1 pad
#define NM2  10    // deg<=2 monomials
#define TILE 128
#define NCHUNK 3
#define CTILES 2   // (NPTS/TILE)/NCHUNK

// ---- monomial index helpers (canonical enumerations) -----------------------
// deg<=4 in (a,b,c): a outer, then b, then c
__device__ __forceinline__ int t4i(int a, int b, int c) {
  int t = 0;
  for (int aa = 0; aa < a; ++aa) t += (5 - aa) * (6 - aa) / 2;
  for (int bb = 0; bb < b; ++bb) t += (5 - a - bb);
  return t + c;
}
// deg<=2 in (a,b,c)
__device__ __forceinline__ int t2i(int a, int b, int c) {
  int t = 0;
  for (int aa = 0; aa < a; ++aa) t += (3 - aa) * (4 - aa) / 2;
  for (int bb = 0; bb < b; ++bb) t += (3 - a - bb);
  return t + c;
}
// deg<=4 in 2 vars (i,j): i outer
__device__ __forceinline__ int s2i(int i, int j) {
  int t = 0;
  for (int ii = 0; ii < i; ++ii) t += (5 - ii);
  return t + j;
}

// ---------------------------------------------------------------------------
// P1: norms; C1m (C x 10, deg<=2 monomials); A2m/B2m; C2m (C x 35 -> pad 36)
// ---------------------------------------------------------------------------
__global__ __launch_bounds__(256) void k_pre1(
    const float* __restrict__ x,
    const float* __restrict__ Wa1, const float* __restrict__ ba1,
    const float* __restrict__ Wb1, const float* __restrict__ bb1,
    const float* __restrict__ Wa2, const float* __restrict__ ba2,
    const float* __restrict__ Wb2, const float* __restrict__ bb2,
    float* __restrict__ norms, float* __restrict__ C2m) {
  __shared__ float C1m[CCH][NM2];
  __shared__ float A2m[CCH][NM2];
  __shared__ float B2m[CCH][NM2];
  const int tid = threadIdx.x;

  for (int i = tid; i < NPTS; i += 256) {
    float a = x[3*i], b = x[3*i+1], c = x[3*i+2];
    norms[i] = sqrtf(a*a + b*b + c*c);
  }
  if (tid < CCH) {
    const int c = tid;
    float La[4] = {Wa1[3*c], Wa1[3*c+1], Wa1[3*c+2], ba1[c]};
    float Lb[4] = {Wb1[3*c], Wb1[3*c+1], Wb1[3*c+2], bb1[c]};
    const int pe[4][3] = {{1,0,0},{0,1,0},{0,0,1},{0,0,0}};
    float acc[NM2];
    for (int t = 0; t < NM2; ++t) acc[t] = 0.f;
    for (int p = 0; p < 4; ++p)
      for (int q = 0; q < 4; ++q)
        acc[t2i(pe[p][0]+pe[q][0], pe[p][1]+pe[q][1], pe[p][2]+pe[q][2])]
            += La[p]*Lb[q];
    for (int t = 0; t < NM2; ++t) C1m[c][t] = acc[t];
  }
  __syncthreads();
  for (int idx = tid; idx < CCH*NM2; idx += 256) {
    const int c = idx / NM2, t = idx % NM2;
    float sa = 0.f, sb = 0.f;
    for (int k = 0; k < CCH; ++k) {
      const float v = C1m[k][t];
      sa += Wa2[c*CCH + k] * v;
      sb += Wb2[c*CCH + k] * v;
    }
    if (t == 0) { sa += ba2[c]; sb += bb2[c]; }  // constant monomial
    A2m[c][t] = sa; B2m[c][t] = sb;
  }
  __syncthreads();
  if (tid < CCH) {
    const int c = tid;
    int me[NM2][3];
    { int t = 0;
      for (int a = 0; a <= 2; ++a)
        for (int b = 0; b <= 2-a; ++b)
          for (int cc = 0; cc <= 2-a-b; ++cc) { me[t][0]=a; me[t][1]=b; me[t][2]=cc; ++t; } }
    float acc[35];
    for (int t = 0; t < 35; ++t) acc[t] = 0.f;
    for (int s = 0; s < NM2; ++s)
      for (int t = 0; t < NM2; ++t)
        acc[t4i(me[s][0]+me[t][0], me[s][1]+me[t][1], me[s][2]+me[t][2])]
            += A2m[c][s]*B2m[c][t];
    for (int t = 0; t < 35; ++t) C2m[c*NM4 + t] = acc[t];
    C2m[c*NM4 + 35] = 0.f;
  }
}

// ---------------------------------------------------------------------------
// P2: A3mT[j][c] = (Wa3 @ C2m)(c,j) + bias at const monomial. Transposed for
// coalesced per-channel loads in the sweep kernels.
// ---------------------------------------------------------------------------
__global__ void k_pre2(const float* __restrict__ Wa3, const float* __restrict__ ba3,
                       const float* __restrict__ Wb3, const float* __restrict__ bb3,
                       const float* __restrict__ C2m,
                       float* __restrict__ A3mT, float* __restrict__ B3mT) {
  const int c = blockIdx.x;
  const int j = threadIdx.x;
  if (j >= NM4) return;
  float sa = 0.f, sb = 0.f;
  if (j < 35) {
    for (int k = 0; k < CCH; ++k) {
      const float v = C2m[k*NM4 + j];
      sa += Wa3[c*CCH + k] * v;
      sb += Wb3[c*CCH + k] * v;
    }
    if (j == 0) { sa += ba3[c]; sb += bb3[c]; }
  }
  A3mT[j*CCH + c] = sa;
  B3mT[j*CCH + c] = sb;
}

// ---------------------------------------------------------------------------
// Kernel A: block = (row m, chunk). 128 threads = channels. Fold u-powers into
// 15 coeffs, online softmax over this chunk's 256 n's. Partial (M, S) out.
// ---------------------------------------------------------------------------
__global__ __launch_bounds__(128) void k_rows(
    const float* __restrict__ x, const float* __restrict__ norms,
    const float* __restrict__ A3mT, const float* __restrict__ B3mT,
    float* __restrict__ Mpart, float* __restrict__ Spart) {
  __shared__ __align__(16) float wlds[TILE][16];
  const int c = threadIdx.x;
  const int m = blockIdx.x;
  const int chunk = blockIdx.y;

  const float u = norms[m];
  const float xm0 = x[3*m], xm1 = x[3*m+1], xm2 = x[3*m+2];

  float upow[5]; upow[0] = 1.f;
  #pragma unroll
  for (int b = 1; b < 5; ++b) upow[b] = upow[b-1]*u;

  float cA[16], cB[16];
  {
    int t = 0;
    #pragma unroll
    for (int i = 0; i <= 4; ++i)
      #pragma unroll
      for (int j = 0; i + j <= 4; ++j) {
        float sa = 0.f, sb = 0.f;
        #pragma unroll
        for (int b = 0; i + j + b <= 4; ++b) {
          const int t4 = t4i(i, b, j);          // (deg d, deg u, deg v)
          sa += A3mT[t4*CCH + c]*upow[b];
          sb += B3mT[t4*CCH + c]*upow[b];
        }
        cA[t] = sa; cB[t] = sb; ++t;
      }
    cA[15] = 0.f; cB[15] = 0.f;
  }

  float mrun = -INFINITY, srun = 0.f;

  for (int tt = 0; tt < CTILES; ++tt) {
    const int t0 = (chunk*CTILES + tt) * TILE;
    __syncthreads();
    {
      const int n = t0 + c;
      const float v = norms[n];
      const float dot = xm0*x[3*n] + xm1*x[3*n+1] + xm2*x[3*n+2];
      float d2 = u*u + v*v - 2.f*dot;
      float d  = (d2 > 0.f) ? sqrtf(d2) : 0.f;
      float dp[5], vp[5];
      dp[0] = 1.f; vp[0] = 1.f;
      #pragma unroll
      for (int i = 1; i < 5; ++i) { dp[i] = dp[i-1]*d; vp[i] = vp[i-1]*v; }
      float wv[16]; int t = 0;
      #pragma unroll
      for (int i = 0; i <= 4; ++i)
        #pragma unroll
        for (int j = 0; i + j <= 4; ++j) wv[t++] = dp[i]*vp[j];
      wv[15] = 0.f;
      float4* dst = (float4*)&wlds[c][0];
      dst[0] = make_float4(wv[0],  wv[1],  wv[2],  wv[3]);
      dst[1] = make_float4(wv[4],  wv[5],  wv[6],  wv[7]);
      dst[2] = make_float4(wv[8],  wv[9],  wv[10], wv[11]);
      dst[3] = make_float4(wv[12], wv[13], wv[14], wv[15]);
    }
    __syncthreads();
    #pragma unroll 4
    for (int nn = 0; nn < TILE; ++nn) {
      const float4* pv = (const float4*)&wlds[nn][0];
      const float4 p0 = pv[0], p1 = pv[1], p2 = pv[2], p3 = pv[3];
      float la = cA[0]*p0.x + cA[1]*p0.y + cA[2]*p0.z + cA[3]*p0.w
               + cA[4]*p1.x + cA[5]*p1.y + cA[6]*p1.z + cA[7]*p1.w
               + cA[8]*p2.x + cA[9]*p2.y + cA[10]*p2.z + cA[11]*p2.w
               + cA[12]*p3.x + cA[13]*p3.y + cA[14]*p3.z;
      float lb = cB[0]*p0.x + cB[1]*p0.y + cB[2]*p0.z + cB[3]*p0.w
               + cB[4]*p1.x + cB[5]*p1.y + cB[6]*p1.z + cB[7]*p1.w
               + cB[8]*p2.x + cB[9]*p2.y + cB[10]*p2.z + cB[11]*p2.w
               + cB[12]*p3.x + cB[13]*p3.y + cB[14]*p3.z;
      const float h = la*lb;
      const float mnew = fmaxf(mrun, h);
      srun = srun*__expf(mrun - mnew) + __expf(h - mnew);
      mrun = mnew;
    }
  }
  const int idx = m*CCH + c;
  Mpart[chunk*(NPTS*CCH) + idx] = mrun;
  Spart[chunk*(NPTS*CCH) + idx] = srun;
}

// ---------------------------------------------------------------------------
// Merge partial softmax stats: M = max, Sinv = 1/sum(rescaled).
// ---------------------------------------------------------------------------
__global__ __launch_bounds__(256) void k_rowmerge(
    const float* __restrict__ Mpart, const float* __restrict__ Spart,
    float* __restrict__ Mfull, float* __restrict__ Sinv) {
  const int idx = blockIdx.x*256 + threadIdx.x;
  const int P = NPTS*CCH;
  const float m0 = Mpart[idx], m1 = Mpart[P + idx], m2 = Mpart[2*P + idx];
  const float M = fmaxf(m0, fmaxf(m1, m2));
  const float S = Spart[idx]*__expf(m0 - M)
                + Spart[P + idx]*__expf(m1 - M)
                + Spart[2*P + idx]*__expf(m2 - M);
  Mfull[idx] = M;
  Sinv[idx] = 1.f / S;
}

// ---------------------------------------------------------------------------
// Kernel B: block = (col n, chunk). Fold v-powers; accumulate partial
// colsum[n,c] over this chunk's 256 m's.
// ---------------------------------------------------------------------------
__global__ __launch_bounds__(128) void k_cols(
    const float* __restrict__ x, const float* __restrict__ norms,
    const float* __restrict__ A3mT, const float* __restrict__ B3mT,
    const float* __restrict__ Mfull, const float* __restrict__ Sinv,
    float* __restrict__ cpart) {
  __shared__ __align__(16) float wlds[TILE][16];
  const int c = threadIdx.x;
  const int n = blockIdx.x;
  const int chunk = blockIdx.y;

  const float v = norms[n];
  const float xn0 = x[3*n], xn1 = x[3*n+1], xn2 = x[3*n+2];

  float vpow[5]; vpow[0] = 1.f;
  #pragma unroll
  for (int b = 1; b < 5; ++b) vpow[b] = vpow[b-1]*v;

  float cA[16], cB[16];
  {
    int t = 0;
    #pragma unroll
    for (int i = 0; i <= 4; ++i)
      #pragma unroll
      for (int j = 0; i + j <= 4; ++j) {     // j = deg u
        float sa = 0.f, sb = 0.f;
        #pragma unroll
        for (int b = 0; i + j + b <= 4; ++b) {
          const int t4 = t4i(i, j, b);        // (deg d, deg u, deg v)
          sa += A3mT[t4*CCH + c]*vpow[b];
          sb += B3mT[t4*CCH + c]*vpow[b];
        }
        cA[t] = sa; cB[t] = sb; ++t;
      }
    cA[15] = 0.f; cB[15] = 0.f;
  }

  float csum = 0.f;

  for (int tt = 0; tt < CTILES; ++tt) {
    const int t0 = (chunk*CTILES + tt) * TILE;
    __syncthreads();
    {
      const int mm = t0 + c;
      const float uu = norms[mm];
      const float dot = xn0*x[3*mm] + xn1*x[3*mm+1] + xn2*x[3*mm+2];
      float d2 = uu*uu + v*v - 2.f*dot;
      float d  = (d2 > 0.f) ? sqrtf(d2) : 0.f;
      float dp[5], up[5];
      dp[0] = 1.f; up[0] = 1.f;
      #pragma unroll
      for (int i = 1; i < 5; ++i) { dp[i] = dp[i-1]*d; up[i] = up[i-1]*uu; }
      float wv[16]; int t = 0;
      #pragma unroll
      for (int i = 0; i <= 4; ++i)
        #pragma unroll
        for (int j = 0; i + j <= 4; ++j) wv[t++] = dp[i]*up[j];
      wv[15] = 0.f;
      float4* dst = (float4*)&wlds[c][0];
      dst[0] = make_float4(wv[0],  wv[1],  wv[2],  wv[3]);
      dst[1] = make_float4(wv[4],  wv[5],  wv[6],  wv[7]);
      dst[2] = make_float4(wv[8],  wv[9],  wv[10], wv[11]);
      dst[3] = make_float4(wv[12], wv[13], wv[14], wv[15]);
    }
    __syncthreads();
    #pragma unroll 4
    for (int nn = 0; nn < TILE; ++nn) {
      const float4* pv = (const float4*)&wlds[nn][0];
      const float4 p0 = pv[0], p1 = pv[1], p2 = pv[2], p3 = pv[3];
      float la = cA[0]*p0.x + cA[1]*p0.y + cA[2]*p0.z + cA[3]*p0.w
               + cA[4]*p1.x + cA[5]*p1.y + cA[6]*p1.z + cA[7]*p1.w
               + cA[8]*p2.x + cA[9]*p2.y + cA[10]*p2.z + cA[11]*p2.w
               + cA[12]*p3.x + cA[13]*p3.y + cA[14]*p3.z;
      float lb = cB[0]*p0.x + cB[1]*p0.y + cB[2]*p0.z + cB[3]*p0.w
               + cB[4]*p1.x + cB[5]*p1.y + cB[6]*p1.z + cB[7]*p1.w
               + cB[8]*p2.x + cB[9]*p2.y + cB[10]*p2.z + cB[11]*p2.w
               + cB[12]*p3.x + cB[13]*p3.y + cB[14]*p3.z;
      const float h = la*lb;
      const int mg = t0 + nn;
      csum += __expf(h - Mfull[mg*CCH + c]) * Sinv[mg*CCH + c];
    }
  }
  cpart[chunk*(NPTS*CCH) + n*CCH + c] = csum;
}

// ---------------------------------------------------------------------------
// Merge colsum chunks + x-weighted aggregation: apart[i][b][c].
// ---------------------------------------------------------------------------
__global__ __launch_bounds__(128) void k_colmerge(
    const float* __restrict__ x, const float* __restrict__ cpart,
    float* __restrict__ apart) {
  const int c = threadIdx.x;
  const int b = blockIdx.x;   // 6 blocks of 128 n's
  const int P = NPTS*CCH;
  float a0 = 0.f, a1 = 0.f, a2 = 0.f;
  for (int k = 0; k < TILE; ++k) {
    const int n = b*TILE + k;
    const float cs = cpart[n*CCH + c] + cpart[P + n*CCH + c] + cpart[2*P + n*CCH + c];
    a0 += cs*x[3*n]; a1 += cs*x[3*n+1]; a2 += cs*x[3*n+2];
  }
  apart[(0*6 + b)*CCH + c] = a0;
  apart[(1*6 + b)*CCH + c] = a1;
  apart[(2*6 + b)*CCH + c] = a2;
}

// ---------------------------------------------------------------------------
// Final: a_i[c] = sum_b apart; out = Wf contraction; out[0:3] = x[0].
// ---------------------------------------------------------------------------
__global__ __launch_bounds__(128) void k_final(
    const float* __restrict__ x, const float* __restrict__ apart,
    const float* __restrict__ Wf, float* __restrict__ out) {
  __shared__ float red[CCH][6];
  const int c = threadIdx.x;
  float a0 = 0.f, a1 = 0.f, a2 = 0.f;
  for (int b = 0; b < 6; ++b) {
    a0 += apart[(0*6 + b)*CCH + c];
    a1 += apart[(1*6 + b)*CCH + c];
    a2 += apart[(2*6 + b)*CCH + c];
  }
  const float w0 = Wf[c], w1 = Wf[CCH + c];
  red[c][0] = w0*a0; red[c][1] = w0*a1; red[c][2] = w0*a2;
  red[c][3] = w1*a0; red[c][4] = w1*a1; red[c][5] = w1*a2;
  __syncthreads();
  if (c < 6) {
    float s = 0.f;
    for (int k = 0; k < CCH; ++k) s += red[k][c];
    out[3 + c] = s;
  }
  if (c < 3) out[c] = x[c];
}

// ---------------------------------------------------------------------------
extern "C" void kernel_launch(void* const* d_in, const int* in_sizes, int n_in,
                              void* d_out, int out_size, void* d_ws, size_t ws_size,
                              hipStream_t stream) {
  const float* x   = (const float*)d_in[0];
  const float* Wa1 = (const float*)d_in[1];
  const float* ba1 = (const float*)d_in[2];
  const float* Wb1 = (const float*)d_in[3];
  const float* bb1 = (const float*)d_in[4];
  const float* Wa2 = (const float*)d_in[5];
  const float* ba2 = (const float*)d_in[6];
  const float* Wb2 = (const float*)d_in[7];
  const float* bb2 = (const float*)d_in[8];
  const float* Wa3 = (const float*)d_in[9];
  const float* ba3 = (const float*)d_in[10];
  const float* Wb3 = (const float*)d_in[11];
  const float* bb3 = (const float*)d_in[12];
  const float* Wf  = (const float*)d_in[13];
  float* out = (float*)d_out;

  const int P = NPTS*CCH;
  float* ws     = (float*)d_ws;
  float* norms  = ws;                      // 768
  float* C2m    = norms + NPTS;            // 128*36
  float* A3mT   = C2m   + CCH*NM4;         // 36*128
  float* B3mT   = A3mT  + NM4*CCH;         // 36*128
  float* Mpart  = B3mT  + NM4*CCH;         // 3*98304
  float* Spart  = Mpart + NCHUNK*P;        // 3*98304
  float* Mfull  = Spart + NCHUNK*P;        // 98304
  float* Sinv   = Mfull + P;               // 98304
  float* cpart  = Sinv  + P;               // 3*98304
  float* apart  = cpart + NCHUNK*P;        // 18*128

  hipLaunchKernelGGL(k_pre1, dim3(1), dim3(256), 0, stream,
                     x, Wa1, ba1, Wb1, bb1, Wa2, ba2, Wb2, bb2, norms, C2m);
  hipLaunchKernelGGL(k_pre2, dim3(CCH), dim3(64), 0, stream,
                     Wa3, ba3, Wb3, bb3, C2m, A3mT, B3mT);
  hipLaunchKernelGGL(k_rows, dim3(NPTS, NCHUNK), dim3(128), 0, stream,
                     x, norms, A3mT, B3mT, Mpart, Spart);
  hipLaunchKernelGGL(k_rowmerge, dim3(P/256), dim3(256), 0, stream,
                     Mpart, Spart, Mfull, Sinv);
  hipLaunchKernelGGL(k_cols, dim3(NPTS, NCHUNK), dim3(128), 0, stream,
                     x, norms, A3mT, B3mT, Mfull, Sinv, cpart);
  hipLaunchKernelGGL(k_colmerge, dim3(NPTS/TILE), dim3(128), 0, stream,
                     x, cpart, apart);
  hipLaunchKernelGGL(k_final, dim3(1), dim3(128), 0, stream,
                     x, apart, Wf, out);
}

// Round 4
// 222.030 us; speedup vs baseline: 3.5011x; 1.3616x over previous
//
#include <hip/hip_runtime.h>

#define NPTS 768
#define CCH  128
#define NM4  36    // 35 deg<=4 monomials in (d,u,v) + 1 pad
#define NM2  10    // deg<=2 monomials
#define TILE 128
#define NCHUNK 6   // one 128-tile of n per block
#define PAIR (NPTS*CCH)
#define LOG2E 1.4426950408889634f

__device__ __forceinline__ float fast_exp2(float x) {
  return __builtin_amdgcn_exp2f(x);   // v_exp_f32 (base-2)
}

// ---- monomial index helpers (compile-time foldable under full unroll) ------
__device__ __forceinline__ int t4i(int a, int b, int c) {
  int t = 0;
  for (int aa = 0; aa < a; ++aa) t += (5 - aa) * (6 - aa) / 2;
  for (int bb = 0; bb < b; ++bb) t += (5 - a - bb);
  return t + c;
}
__device__ __forceinline__ int t2i(int a, int b, int c) {
  int t = 0;
  for (int aa = 0; aa < a; ++aa) t += (3 - aa) * (4 - aa) / 2;
  for (int bb = 0; bb < b; ++bb) t += (3 - a - bb);
  return t + c;
}

// ---------------------------------------------------------------------------
// P1: norms; C1m (C x 10); A2m/B2m = W2-fold; C2m (C x 35, padded to 36)
// ---------------------------------------------------------------------------
__global__ __launch_bounds__(256) void k_pre1(
    const float* __restrict__ x,
    const float* __restrict__ Wa1, const float* __restrict__ ba1,
    const float* __restrict__ Wb1, const float* __restrict__ bb1,
    const float* __restrict__ Wa2, const float* __restrict__ ba2,
    const float* __restrict__ Wb2, const float* __restrict__ bb2,
    float* __restrict__ norms, float* __restrict__ C2m) {
  __shared__ float C1m[CCH][NM2];
  __shared__ float A2m[CCH][NM2];
  __shared__ float B2m[CCH][NM2];
  const int tid = threadIdx.x;

  for (int i = tid; i < NPTS; i += 256) {
    float a = x[3*i], b = x[3*i+1], c = x[3*i+2];
    norms[i] = sqrtf(a*a + b*b + c*c);
  }
  if (tid < CCH) {
    const int c = tid;
    float La[4] = {Wa1[3*c], Wa1[3*c+1], Wa1[3*c+2], ba1[c]};
    float Lb[4] = {Wb1[3*c], Wb1[3*c+1], Wb1[3*c+2], bb1[c]};
    float acc[NM2];
    #pragma unroll
    for (int t = 0; t < NM2; ++t) acc[t] = 0.f;
    // exponent vectors for (d,u,v): idx 0->d, 1->u, 2->v, 3->const
    #pragma unroll
    for (int p = 0; p < 4; ++p)
      #pragma unroll
      for (int q = 0; q < 4; ++q) {
        const int ea = (p==0) + (q==0);
        const int eb = (p==1) + (q==1);
        const int ec = (p==2) + (q==2);
        acc[t2i(ea, eb, ec)] += La[p]*Lb[q];
      }
    #pragma unroll
    for (int t = 0; t < NM2; ++t) C1m[c][t] = acc[t];
  }
  __syncthreads();
  for (int idx = tid; idx < CCH*NM2; idx += 256) {
    const int c = idx / NM2, t = idx % NM2;
    float sa = 0.f, sb = 0.f;
    for (int k = 0; k < CCH; ++k) {
      const float v = C1m[k][t];
      sa += Wa2[c*CCH + k] * v;
      sb += Wb2[c*CCH + k] * v;
    }
    if (t == 0) { sa += ba2[c]; sb += bb2[c]; }  // constant monomial
    A2m[c][t] = sa; B2m[c][t] = sb;
  }
  __syncthreads();
  if (tid < CCH) {
    const int c = tid;
    float acc[35];
    #pragma unroll
    for (int t = 0; t < 35; ++t) acc[t] = 0.f;
    #pragma unroll
    for (int a1 = 0; a1 <= 2; ++a1)
      #pragma unroll
      for (int b1 = 0; b1 <= 2; ++b1)
        #pragma unroll
        for (int c1 = 0; c1 <= 2; ++c1)
          if (a1 + b1 + c1 <= 2) {
            const float av = A2m[c][t2i(a1,b1,c1)];
            #pragma unroll
            for (int a2 = 0; a2 <= 2; ++a2)
              #pragma unroll
              for (int b2 = 0; b2 <= 2; ++b2)
                #pragma unroll
                for (int c2 = 0; c2 <= 2; ++c2)
                  if (a2 + b2 + c2 <= 2)
                    acc[t4i(a1+a2, b1+b2, c1+c2)] += av * B2m[c][t2i(a2,b2,c2)];
          }
    #pragma unroll
    for (int t = 0; t < 35; ++t) C2m[c*NM4 + t] = acc[t];
    C2m[c*NM4 + 35] = 0.f;
  }
}

// ---------------------------------------------------------------------------
// P2: A3mT[j][c] = (Wa3 @ C2m)(c,j) + bias at constant monomial. Transposed.
// ---------------------------------------------------------------------------
__global__ void k_pre2(const float* __restrict__ Wa3, const float* __restrict__ ba3,
                       const float* __restrict__ Wb3, const float* __restrict__ bb3,
                       const float* __restrict__ C2m,
                       float* __restrict__ A3mT, float* __restrict__ B3mT) {
  const int c = blockIdx.x;
  const int j = threadIdx.x;
  if (j >= NM4) return;
  float sa = 0.f, sb = 0.f;
  if (j < 35) {
    for (int k = 0; k < CCH; ++k) {
      const float v = C2m[k*NM4 + j];
      sa += Wa3[c*CCH + k] * v;
      sb += Wb3[c*CCH + k] * v;
    }
    if (j == 0) { sa += ba3[c]; sb += bb3[c]; }
  }
  A3mT[j*CCH + c] = sa;
  B3mT[j*CCH + c] = sb;
}

// ---------------------------------------------------------------------------
// k_main: block = (row m, n-chunk of 128). 128 threads = channels.
// Single sweep: online softmax in log2 domain + x-weighted accumulators.
// Outputs per-chunk partials (M, S, a0, a1, a2).
// ---------------------------------------------------------------------------
__global__ __launch_bounds__(128) void k_main(
    const float* __restrict__ x, const float* __restrict__ norms,
    const float* __restrict__ A3mT, const float* __restrict__ B3mT,
    float* __restrict__ Mp, float* __restrict__ Sp,
    float* __restrict__ A0p, float* __restrict__ A1p, float* __restrict__ A2p) {
  __shared__ __align__(16) float wlds[TILE][16];
  __shared__ __align__(16) float xt[TILE][4];
  const int c = threadIdx.x;
  const int m = blockIdx.x;
  const int chunk = blockIdx.y;

  const float u = norms[m];
  const float xm0 = x[3*m], xm1 = x[3*m+1], xm2 = x[3*m+2];

  // Build this thread's psi row (n = chunk*128 + c) into LDS.
  {
    const int n = chunk*TILE + c;
    const float v = norms[n];
    const float x0 = x[3*n], x1 = x[3*n+1], x2 = x[3*n+2];
    const float dot = xm0*x0 + xm1*x1 + xm2*x2;
    float d2 = u*u + v*v - 2.f*dot;
    float d  = (d2 > 0.f) ? sqrtf(d2) : 0.f;
    float dp[5], vp[5];
    dp[0] = 1.f; vp[0] = 1.f;
    #pragma unroll
    for (int i = 1; i < 5; ++i) { dp[i] = dp[i-1]*d; vp[i] = vp[i-1]*v; }
    float wv[16]; int t = 0;
    #pragma unroll
    for (int i = 0; i <= 4; ++i)
      #pragma unroll
      for (int j = 0; i + j <= 4; ++j) wv[t++] = dp[i]*vp[j];
    wv[15] = 0.f;
    float4* dst = (float4*)&wlds[c][0];
    dst[0] = make_float4(wv[0],  wv[1],  wv[2],  wv[3]);
    dst[1] = make_float4(wv[4],  wv[5],  wv[6],  wv[7]);
    dst[2] = make_float4(wv[8],  wv[9],  wv[10], wv[11]);
    dst[3] = make_float4(wv[12], wv[13], wv[14], wv[15]);
    *(float4*)&xt[c][0] = make_float4(x0, x1, x2, 0.f);
  }

  // Fold u-powers into per-channel coefficients; log2e folded into cA.
  float upow[5]; upow[0] = 1.f;
  #pragma unroll
  for (int b = 1; b < 5; ++b) upow[b] = upow[b-1]*u;
  float cA[16], cB[16];
  {
    int t = 0;
    #pragma unroll
    for (int i = 0; i <= 4; ++i)
      #pragma unroll
      for (int j = 0; i + j <= 4; ++j) {
        float sa = 0.f, sb = 0.f;
        #pragma unroll
        for (int b = 0; i + j + b <= 4; ++b) {
          const int t4 = t4i(i, b, j);   // (deg d, deg u, deg v)
          sa += A3mT[t4*CCH + c]*upow[b];
          sb += B3mT[t4*CCH + c]*upow[b];
        }
        cA[t] = sa*LOG2E; cB[t] = sb; ++t;
      }
    cA[15] = 0.f; cB[15] = 0.f;
  }

  __syncthreads();

  float mrun = -INFINITY, srun = 0.f, a0 = 0.f, a1 = 0.f, a2 = 0.f;
  #pragma unroll 2
  for (int nn = 0; nn < TILE; ++nn) {
    const float4* pv = (const float4*)&wlds[nn][0];
    const float4 p0 = pv[0], p1 = pv[1], p2 = pv[2], p3 = pv[3];
    const float4 xq = *(const float4*)&xt[nn][0];
    float laA = cA[0]*p0.x + cA[1]*p0.y + cA[2]*p0.z + cA[3]*p0.w
              + cA[4]*p1.x + cA[5]*p1.y + cA[6]*p1.z + cA[7]*p1.w;
    float laB = cA[8]*p2.x + cA[9]*p2.y + cA[10]*p2.z + cA[11]*p2.w
              + cA[12]*p3.x + cA[13]*p3.y + cA[14]*p3.z;
    float lbA = cB[0]*p0.x + cB[1]*p0.y + cB[2]*p0.z + cB[3]*p0.w
              + cB[4]*p1.x + cB[5]*p1.y + cB[6]*p1.z + cB[7]*p1.w;
    float lbB = cB[8]*p2.x + cB[9]*p2.y + cB[10]*p2.z + cB[11]*p2.w
              + cB[12]*p3.x + cB[13]*p3.y + cB[14]*p3.z;
    const float h2 = (laA + laB) * (lbA + lbB);   // h * log2e
    const float mnew = fmaxf(mrun, h2);
    const float scale = fast_exp2(mrun - mnew);
    const float e = fast_exp2(h2 - mnew);
    srun = fmaf(srun, scale, e);
    a0 = fmaf(a0, scale, e*xq.x);
    a1 = fmaf(a1, scale, e*xq.y);
    a2 = fmaf(a2, scale, e*xq.z);
    mrun = mnew;
  }
  const int idx = chunk*PAIR + m*CCH + c;
  Mp[idx] = mrun; Sp[idx] = srun;
  A0p[idx] = a0; A1p[idx] = a1; A2p[idx] = a2;
}

// ---------------------------------------------------------------------------
// Merge chunk partials per (m,c): G_i[m,c] = sum_n att[m,n,c]*x[n,i].
// ---------------------------------------------------------------------------
__global__ __launch_bounds__(256) void k_merge(
    const float* __restrict__ Mp, const float* __restrict__ Sp,
    const float* __restrict__ A0p, const float* __restrict__ A1p,
    const float* __restrict__ A2p,
    float* __restrict__ G0, float* __restrict__ G1, float* __restrict__ G2) {
  const int gid = blockIdx.x*256 + threadIdx.x;
  float mv[NCHUNK];
  float M = -INFINITY;
  #pragma unroll
  for (int ch = 0; ch < NCHUNK; ++ch) {
    mv[ch] = Mp[ch*PAIR + gid];
    M = fmaxf(M, mv[ch]);
  }
  float W = 0.f, g0 = 0.f, g1 = 0.f, g2 = 0.f;
  #pragma unroll
  for (int ch = 0; ch < NCHUNK; ++ch) {
    const float s = fast_exp2(mv[ch] - M);
    W  = fmaf(Sp [ch*PAIR + gid], s, W);
    g0 = fmaf(A0p[ch*PAIR + gid], s, g0);
    g1 = fmaf(A1p[ch*PAIR + gid], s, g1);
    g2 = fmaf(A2p[ch*PAIR + gid], s, g2);
  }
  const float inv = 1.f / W;
  G0[gid] = g0*inv; G1[gid] = g1*inv; G2[gid] = g2*inv;
}

// ---------------------------------------------------------------------------
// Reduce over m in blocks of 128: apart[i][mg][c] = sum G_i[m,c].
// ---------------------------------------------------------------------------
__global__ __launch_bounds__(128) void k_reduce(
    const float* __restrict__ G0, const float* __restrict__ G1,
    const float* __restrict__ G2, float* __restrict__ apart) {
  const int c = threadIdx.x;
  const int i = blockIdx.x, mg = blockIdx.y;
  const float* G = (i == 0) ? G0 : (i == 1) ? G1 : G2;
  float s = 0.f;
  for (int k = 0; k < 128; ++k) s += G[(mg*128 + k)*CCH + c];
  apart[(i*6 + mg)*CCH + c] = s;
}

// ---------------------------------------------------------------------------
// Final: a_i[c] = sum over 6 partials; out = Wf contraction; out[0:3] = x[0].
// ---------------------------------------------------------------------------
__global__ __launch_bounds__(128) void k_final(
    const float* __restrict__ x, const float* __restrict__ apart,
    const float* __restrict__ Wf, float* __restrict__ out) {
  __shared__ float red[CCH][6];
  const int c = threadIdx.x;
  float a0 = 0.f, a1 = 0.f, a2 = 0.f;
  #pragma unroll
  for (int b = 0; b < 6; ++b) {
    a0 += apart[(0*6 + b)*CCH + c];
    a1 += apart[(1*6 + b)*CCH + c];
    a2 += apart[(2*6 + b)*CCH + c];
  }
  const float w0 = Wf[c], w1 = Wf[CCH + c];
  red[c][0] = w0*a0; red[c][1] = w0*a1; red[c][2] = w0*a2;
  red[c][3] = w1*a0; red[c][4] = w1*a1; red[c][5] = w1*a2;
  __syncthreads();
  if (c < 6) {
    float s = 0.f;
    for (int k = 0; k < CCH; ++k) s += red[k][c];
    out[3 + c] = s;
  }
  if (c < 3) out[c] = x[c];
}

// ---------------------------------------------------------------------------
extern "C" void kernel_launch(void* const* d_in, const int* in_sizes, int n_in,
                              void* d_out, int out_size, void* d_ws, size_t ws_size,
                              hipStream_t stream) {
  const float* x   = (const float*)d_in[0];
  const float* Wa1 = (const float*)d_in[1];
  const float* ba1 = (const float*)d_in[2];
  const float* Wb1 = (const float*)d_in[3];
  const float* bb1 = (const float*)d_in[4];
  const float* Wa2 = (const float*)d_in[5];
  const float* ba2 = (const float*)d_in[6];
  const float* Wb2 = (const float*)d_in[7];
  const float* bb2 = (const float*)d_in[8];
  const float* Wa3 = (const float*)d_in[9];
  const float* ba3 = (const float*)d_in[10];
  const float* Wb3 = (const float*)d_in[11];
  const float* bb3 = (const float*)d_in[12];
  const float* Wf  = (const float*)d_in[13];
  float* out = (float*)d_out;

  float* ws     = (float*)d_ws;
  float* norms  = ws;                      // 768
  float* C2m    = norms + NPTS;            // 128*36
  float* A3mT   = C2m   + CCH*NM4;         // 36*128
  float* B3mT   = A3mT  + NM4*CCH;         // 36*128
  float* Mp     = B3mT  + NM4*CCH;         // 6*98304
  float* Sp     = Mp    + NCHUNK*PAIR;     // 6*98304
  float* A0p    = Sp    + NCHUNK*PAIR;     // 6*98304
  float* A1p    = A0p   + NCHUNK*PAIR;     // 6*98304
  float* A2p    = A1p   + NCHUNK*PAIR;     // 6*98304
  float* G0     = A2p   + NCHUNK*PAIR;     // 98304
  float* G1     = G0    + PAIR;            // 98304
  float* G2     = G1    + PAIR;            // 98304
  float* apart  = G2    + PAIR;            // 18*128   (total ~13 MB)

  hipLaunchKernelGGL(k_pre1, dim3(1), dim3(256), 0, stream,
                     x, Wa1, ba1, Wb1, bb1, Wa2, ba2, Wb2, bb2, norms, C2m);
  hipLaunchKernelGGL(k_pre2, dim3(CCH), dim3(64), 0, stream,
                     Wa3, ba3, Wb3, bb3, C2m, A3mT, B3mT);
  hipLaunchKernelGGL(k_main, dim3(NPTS, NCHUNK), dim3(128), 0, stream,
                     x, norms, A3mT, B3mT, Mp, Sp, A0p, A1p, A2p);
  hipLaunchKernelGGL(k_merge, dim3(PAIR/256), dim3(256), 0, stream,
                     Mp, Sp, A0p, A1p, A2p, G0, G1, G2);
  hipLaunchKernelGGL(k_reduce, dim3(3, 6), dim3(128), 0, stream,
                     G0, G1, G2, apart);
  hipLaunchKernelGGL(k_final, dim3(1), dim3(128), 0, stream,
                     x, apart, Wf, out);
}